// Round 3
// baseline (30504.144 us; speedup 1.0000x reference)
//
#include <hip/hip_runtime.h>
#include <stdint.h>

#define T_STEPS 8192
#define K_TAGS 1024
#define D_DIM 1024
#define START_TAG 1022
#define STOP_TAG 1023
#define NEGV (-10000.0f)
#define LOG2E 1.4426950408889634f
#define LN2 0.6931471805599453f
#define CLAMP2 (-1.0e5f)   // stand-in for -inf; exp2(CLAMP2 - M2) == 0 always

#define NBLK 64       // blocks in persistent CRF kernel
#define ROWS_PB 16    // K_TAGS / NBLK rows per block; one WAVE per row
#define C8 8          // float2 cell-pairs per lane (16 prev cells / lane)

// ---- agent-scope (device) 32-bit payload-with-embedded-tag atomics ---------
// Low 8 mantissa bits of the f32 carry the step tag (t & 0xFF). A single
// 4-byte atom is both value and readiness flag: no ordering, no fences.
__device__ __forceinline__ unsigned ld_agent_u32(const unsigned* p) {
  return __hip_atomic_load(p, __ATOMIC_RELAXED, __HIP_MEMORY_SCOPE_AGENT);
}
__device__ __forceinline__ void st_agent_u32(unsigned* p, unsigned v) {
  __hip_atomic_store(p, v, __ATOMIC_RELAXED, __HIP_MEMORY_SCOPE_AGENT);
}
__device__ __forceinline__ unsigned tag_pack(float v, unsigned tag8) {
  return (__float_as_uint(v) & ~0xFFu) | tag8;
}

// ---- workspace init (runs every call; ws is NOT re-poisoned between replays)
// Tag byte 0xFF never matches the first consult of either slot (wants 0 / 1),
// and wipes the previous replay's final tags (which end at tag 0!).
__global__ void init_ws_kernel(unsigned* fvbuf, int* bmax) {
  int i = blockIdx.x * blockDim.x + threadIdx.x;
  if (i < 2 * K_TAGS) fvbuf[i] = 0xFFu;
  if (i == 0) *bmax = 0;  // float 0.0 bits; true max is positive
}

// ---- gates: one wave per step t; t==T_STEPS computes the terminal gate -----
__global__ __launch_bounds__(256) void gate_kernel(
    const float* __restrict__ reps, const float* __restrict__ wc,
    const float* __restrict__ wu, const int* __restrict__ spk,
    float* __restrict__ gate, float* __restrict__ g_term) {
  const int gw = (int)((blockIdx.x * blockDim.x + threadIdx.x) >> 6);  // wave id = t
  const int lane = threadIdx.x & 63;
  if (gw > T_STEPS) return;
  const int tcur = (gw < T_STEPS) ? gw : (T_STEPS - 1);
  const int tprv = (gw < T_STEPS) ? (gw > 0 ? gw - 1 : 0) : (T_STEPS - 1);
  const float* cur = reps + (size_t)tcur * D_DIM;
  const float* prv = reps + (size_t)tprv * D_DIM;
  float sc = 0.f, su = 0.f;
#pragma unroll
  for (int c = 0; c < 4; ++c) {
    const int d = lane * 4 + c * 256;
    float4 rp = *(const float4*)(prv + d);
    float4 rc = *(const float4*)(cur + d);
    float4 w1 = *(const float4*)(wc + d);
    float4 w2 = *(const float4*)(wc + D_DIM + d);
    float4 w3 = *(const float4*)(wu + d);
    float4 w4 = *(const float4*)(wu + D_DIM + d);
    sc += rp.x * w1.x + rp.y * w1.y + rp.z * w1.z + rp.w * w1.w;
    sc += rc.x * w2.x + rc.y * w2.y + rc.z * w2.z + rc.w * w2.w;
    su += rp.x * w3.x + rp.y * w3.y + rp.z * w3.z + rp.w * w3.w;
    su += rc.x * w4.x + rc.y * w4.y + rc.z * w4.z + rc.w * w4.w;
  }
#pragma unroll
  for (int off = 32; off; off >>= 1) {
    sc += __shfl_xor(sc, off);
    su += __shfl_xor(su, off);
  }
  if (lane == 0) {
    if (gw < T_STEPS) {
      bool uc = (gw > 0) && (spk[gw] != 0);
      float x = uc ? sc : su;
      gate[gw] = 1.0f / (1.0f + __expf(-x));
    } else {
      *g_term = 1.0f / (1.0f + __expf(-su));
    }
  }
}

// ---- global max over elementwise max(ti, ta) (for the safe LSE shift) ------
__global__ __launch_bounds__(256) void bmax_kernel(
    const float* __restrict__ ti, const float* __restrict__ ta, int* bmax) {
  size_t i = (size_t)blockIdx.x * blockDim.x + threadIdx.x;
  size_t n = (size_t)K_TAGS * K_TAGS;
  float m = 0.f;  // clamped at 0 so int-compare atomicMax is valid
  for (size_t j = i; j < n; j += (size_t)gridDim.x * blockDim.x)
    m = fmaxf(m, fmaxf(ti[j], ta[j]));
#pragma unroll
  for (int off = 32; off; off >>= 1) m = fmaxf(m, __shfl_xor(m, off));
  if ((threadIdx.x & 63) == 0) atomicMax(bmax, __float_as_int(m));
}

// ---- persistent CRF forward scan -------------------------------------------
// 64 blocks x 1024 threads (16 waves). Wave w of block b owns row r=16b+w:
// 64 lanes x 16 prev cells, lane l owns prevs {2l + 128c : c=0..7}.
// Per step: poll ONE tagged dword/thread -> LDS -> 1 barrier -> M2 from 16
// broadcast words -> 16 exp2 cells -> wave shuffle-sum -> lane0 publishes.
__global__ __launch_bounds__(1024) void crf_kernel(
    const float* __restrict__ feats, const float* __restrict__ ti,
    const float* __restrict__ ta, const float* __restrict__ gate,
    const float* __restrict__ g_term_p, const int* __restrict__ bmax_p,
    unsigned* fvb, float* __restrict__ out) {
  const int b = blockIdx.x;
  const int tid = threadIdx.x;
  const int lane = tid & 63;
  const int w = tid >> 6;             // wave id = local row
  const int r = b * ROWS_PB + w;      // this wave's global row

  __shared__ __align__(16) float fvs[2][K_TAGS];
  __shared__ __align__(16) float wredM[2][16];   // slot-buffered (race-free)
  __shared__ float wredS[16];

  // register-resident, log2-scaled matrix slices (constant across steps)
  float ta2[16], df2[16];
  {
    const float2* taP = reinterpret_cast<const float2*>(ta + (size_t)r * K_TAGS) + lane;
    const float2* tiP = reinterpret_cast<const float2*>(ti + (size_t)r * K_TAGS) + lane;
#pragma unroll
    for (int c = 0; c < C8; ++c) {
      float2 a = taP[64 * c];
      float2 i_ = tiP[64 * c];
      ta2[2 * c] = a.x * LOG2E;
      df2[2 * c] = (i_.x - a.x) * LOG2E;
      ta2[2 * c + 1] = a.y * LOG2E;
      df2[2 * c + 1] = (i_.y - a.y) * LOG2E;
    }
  }
  const float bmax2 = __int_as_float(*bmax_p) * LOG2E;

  // publish initial state s_0 (tag 0) into slot 0
  if (tid < ROWS_PB) {
    int rr = b * ROWS_PB + tid;
    float v = (rr == START_TAG) ? 0.0f : NEGV * LOG2E;
    st_agent_u32(&fvb[rr], tag_pack(v, 0u));
  }

  for (int t = 0; t < T_STEPS; ++t) {
    const int slot = t & 1;
    const unsigned want = (unsigned)(t & 0xFF);
    const float g = gate[t];            // broadcast load, hidden under poll
    float featv = 0.f;
    if (lane == 0) featv = feats[(size_t)t * K_TAGS + r];

    // 1) poll own tagged dword (backoff keeps fabric pressure low)
    unsigned* ep = &fvb[slot * K_TAGS + tid];
    unsigned u = ld_agent_u32(ep);
    while ((u & 0xFFu) != want) {
      __builtin_amdgcn_s_sleep(1);
      u = ld_agent_u32(ep);
    }
    const float v = __uint_as_float(u);

    // 2) stash fv, wave-max -> one barrier -> block max (broadcast reads)
    fvs[slot][tid] = v;
    float m = v;
#pragma unroll
    for (int off = 32; off; off >>= 1) m = fmaxf(m, __shfl_xor(m, off));
    if (lane == 0) wredM[slot][w] = m;
    __syncthreads();
    float4 m0 = *reinterpret_cast<const float4*>(&wredM[slot][0]);
    float4 m1 = *reinterpret_cast<const float4*>(&wredM[slot][4]);
    float4 m2 = *reinterpret_cast<const float4*>(&wredM[slot][8]);
    float4 m3 = *reinterpret_cast<const float4*>(&wredM[slot][12]);
    float mm = fmaxf(fmaxf(fmaxf(m0.x, m0.y), fmaxf(m0.z, m0.w)),
                     fmaxf(fmaxf(m1.x, m1.y), fmaxf(m1.z, m1.w)));
    mm = fmaxf(mm, fmaxf(fmaxf(fmaxf(m2.x, m2.y), fmaxf(m2.z, m2.w)),
                         fmaxf(fmaxf(m3.x, m3.y), fmaxf(m3.z, m3.w))));
    const float M2 = mm + bmax2;

    // 3) 16 cells/lane: acc += 2^(ta2 + g*df2 + fv - M2); conflict-free b64
    float acc = 0.f;
    const float2* fp = reinterpret_cast<const float2*>(&fvs[slot][0]) + lane;
#pragma unroll
    for (int c = 0; c < C8; ++c) {
      float2 f = fp[64 * c];
      acc += exp2f(__builtin_fmaf(g, df2[2 * c], ta2[2 * c]) + (f.x - M2));
      acc += exp2f(__builtin_fmaf(g, df2[2 * c + 1], ta2[2 * c + 1]) + (f.y - M2));
    }
#pragma unroll
    for (int off = 32; off; off >>= 1) acc += __shfl_xor(acc, off);

    // 4) lane0 finalizes + publishes (tag t+1) into the other slot.
    //    clamp: acc==0 would give -inf, whose tagged bits are NaN.
    if (lane == 0) {
      float fvnew = fmaxf(M2 + __log2f(acc) + featv * LOG2E, CLAMP2);
      st_agent_u32(&fvb[(slot ^ 1) * K_TAGS + r],
                   tag_pack(fvnew, (unsigned)((t + 1) & 0xFF)));
    }
  }

  // ---- terminal LSE by block 0 ----------------------------------------------
  if (b == 0) {
    const unsigned want = (unsigned)(T_STEPS & 0xFF);  // 0
    const float gt = *g_term_p;
    const float tis = ti[(size_t)STOP_TAG * K_TAGS + tid];
    const float tas = ta[(size_t)STOP_TAG * K_TAGS + tid];
    unsigned* ep = &fvb[(T_STEPS & 1) * K_TAGS + tid];
    unsigned u = ld_agent_u32(ep);
    while ((u & 0xFFu) != want) {
      __builtin_amdgcn_s_sleep(1);
      u = ld_agent_u32(ep);
    }
    const float term2 = __uint_as_float(u) + (tas + gt * (tis - tas)) * LOG2E;

    float m = term2;
#pragma unroll
    for (int off = 32; off; off >>= 1) m = fmaxf(m, __shfl_xor(m, off));
    if (lane == 0) wredM[0][w] = m;
    __syncthreads();
    float mm = wredM[0][0];
#pragma unroll
    for (int i = 1; i < 16; ++i) mm = fmaxf(mm, wredM[0][i]);
    float e = exp2f(term2 - mm);
#pragma unroll
    for (int off = 32; off; off >>= 1) e += __shfl_xor(e, off);
    if (lane == 0) wredS[w] = e;
    __syncthreads();
    if (tid == 0) {
      float s = 0.f;
#pragma unroll
      for (int i = 0; i < 16; ++i) s += wredS[i];
      out[0] = (mm + __log2f(s)) * LN2;
    }
  }
}

extern "C" void kernel_launch(void* const* d_in, const int* in_sizes, int n_in,
                              void* d_out, int out_size, void* d_ws, size_t ws_size,
                              hipStream_t stream) {
  (void)in_sizes; (void)n_in; (void)out_size; (void)ws_size;
  const float* feats = (const float*)d_in[0];
  const float* reps  = (const float*)d_in[1];
  const float* wc    = (const float*)d_in[2];
  const float* wu    = (const float*)d_in[3];
  const float* ti    = (const float*)d_in[4];
  const float* ta    = (const float*)d_in[5];
  const int*   spk   = (const int*)d_in[6];
  float* out = (float*)d_out;

  // ws layout: fvbuf[2][1024] u32 (8 KiB) | gate[8192] f32 | g_term f32 | bmax i32
  unsigned* fvbuf = (unsigned*)d_ws;
  float* gate  = (float*)((char*)d_ws + 2 * K_TAGS * sizeof(unsigned));
  float* gterm = gate + T_STEPS;
  int*   bmax  = (int*)(gterm + 1);

  init_ws_kernel<<<dim3(8), dim3(256), 0, stream>>>(fvbuf, bmax);
  // 8193 wave-sized jobs, 4 waves per block
  gate_kernel<<<dim3((T_STEPS + 1 + 3) / 4), dim3(256), 0, stream>>>(
      reps, wc, wu, spk, gate, gterm);
  bmax_kernel<<<dim3(512), dim3(256), 0, stream>>>(ti, ta, bmax);
  crf_kernel<<<dim3(NBLK), dim3(1024), 0, stream>>>(feats, ti, ta, gate, gterm,
                                                    bmax, fvbuf, out);
}

// Round 4
// 15933.531 us; speedup vs baseline: 1.9145x; 1.9145x over previous
//
#include <hip/hip_runtime.h>
#include <stdint.h>

#define T_STEPS 8192
#define K_TAGS 1024
#define D_DIM 1024
#define START_TAG 1022
#define STOP_TAG 1023
#define NEGV (-10000.0f)
#define LOG2E 1.4426950408889634f
#define LN2 0.6931471805599453f
#define MARGIN2 40.0f   // lagged-shift slack (log2 units); hard-safe, see notes

#define NBLK 256      // blocks in persistent CRF kernel
#define ROWS_PB 4     // K_TAGS / NBLK rows per block; one WAVE per row
#define C8 8          // float2 cell-pairs per lane (16 prev cells / lane)

#define TAG(u) ((unsigned)((u) >> 32))

// ---- agent-scope (device) 64-bit payload+tag atomics -----------------------
__device__ __forceinline__ unsigned long long ld_agent_u64(const unsigned long long* p) {
  return __hip_atomic_load(p, __ATOMIC_RELAXED, __HIP_MEMORY_SCOPE_AGENT);
}
__device__ __forceinline__ void st_agent_u64(unsigned long long* p, unsigned long long v) {
  __hip_atomic_store(p, v, __ATOMIC_RELAXED, __HIP_MEMORY_SCOPE_AGENT);
}

// ---- workspace init (runs every call; ws is NOT re-poisoned between replays)
__global__ void init_ws_kernel(unsigned long long* fvbuf, int* bmax) {
  int i = blockIdx.x * blockDim.x + threadIdx.x;
  if (i < 2 * K_TAGS) fvbuf[i] = 0ull;   // tag 0 everywhere
  if (i == 0) *bmax = 0;                 // float 0.0 bits; true max is positive
}

// ---- gates: one wave per step t; t==T_STEPS computes the terminal gate -----
__global__ __launch_bounds__(256) void gate_kernel(
    const float* __restrict__ reps, const float* __restrict__ wc,
    const float* __restrict__ wu, const int* __restrict__ spk,
    float* __restrict__ gate, float* __restrict__ g_term) {
  const int gw = (int)((blockIdx.x * blockDim.x + threadIdx.x) >> 6);  // wave id = t
  const int lane = threadIdx.x & 63;
  if (gw > T_STEPS) return;
  const int tcur = (gw < T_STEPS) ? gw : (T_STEPS - 1);
  const int tprv = (gw < T_STEPS) ? (gw > 0 ? gw - 1 : 0) : (T_STEPS - 1);
  const float* cur = reps + (size_t)tcur * D_DIM;
  const float* prv = reps + (size_t)tprv * D_DIM;
  float sc = 0.f, su = 0.f;
#pragma unroll
  for (int c = 0; c < 4; ++c) {
    const int d = lane * 4 + c * 256;
    float4 rp = *(const float4*)(prv + d);
    float4 rc = *(const float4*)(cur + d);
    float4 w1 = *(const float4*)(wc + d);
    float4 w2 = *(const float4*)(wc + D_DIM + d);
    float4 w3 = *(const float4*)(wu + d);
    float4 w4 = *(const float4*)(wu + D_DIM + d);
    sc += rp.x * w1.x + rp.y * w1.y + rp.z * w1.z + rp.w * w1.w;
    sc += rc.x * w2.x + rc.y * w2.y + rc.z * w2.z + rc.w * w2.w;
    su += rp.x * w3.x + rp.y * w3.y + rp.z * w3.z + rp.w * w3.w;
    su += rc.x * w4.x + rc.y * w4.y + rc.z * w4.z + rc.w * w4.w;
  }
#pragma unroll
  for (int off = 32; off; off >>= 1) {
    sc += __shfl_xor(sc, off);
    su += __shfl_xor(su, off);
  }
  if (lane == 0) {
    if (gw < T_STEPS) {
      bool uc = (gw > 0) && (spk[gw] != 0);
      float x = uc ? sc : su;
      gate[gw] = 1.0f / (1.0f + __expf(-x));
    } else {
      *g_term = 1.0f / (1.0f + __expf(-su));
    }
  }
}

// ---- global max over elementwise max(ti, ta) (for the safe LSE shift) ------
__global__ __launch_bounds__(256) void bmax_kernel(
    const float* __restrict__ ti, const float* __restrict__ ta, int* bmax) {
  size_t i = (size_t)blockIdx.x * blockDim.x + threadIdx.x;
  size_t n = (size_t)K_TAGS * K_TAGS;
  float m = 0.f;  // clamped at 0 so int-compare atomicMax is valid
  for (size_t j = i; j < n; j += (size_t)gridDim.x * blockDim.x)
    m = fmaxf(m, fmaxf(ti[j], ta[j]));
#pragma unroll
  for (int off = 32; off; off >>= 1) m = fmaxf(m, __shfl_xor(m, off));
  if ((threadIdx.x & 63) == 0) atomicMax(bmax, __float_as_int(m));
}

// ---- persistent CRF forward scan -------------------------------------------
// r2 skeleton: 256 blocks x 256 threads (4 waves). Wave w of block b owns row
// r=4b+w: 64 lanes x 16 prev cells, lane l owns prevs {2l + 128c : c=0..7}.
// New in r4:
//  * pipelined poll: two staggered in-flight sets of the 4 u64 loads -> the
//    sampling interval of each entry is ~half a load round-trip.
//  * lagged shift: cells use shift = blockmax(fv_{t-1}) + bmax2 + MARGIN2;
//    the wave/block max of fv_t is computed AFTER the publish (off the
//    critical path) and consumed at t+1 via slot-buffered wredM.
__global__ __launch_bounds__(256) void crf_kernel(
    const float* __restrict__ feats, const float* __restrict__ ti,
    const float* __restrict__ ta, const float* __restrict__ gate,
    const float* __restrict__ g_term_p, const int* __restrict__ bmax_p,
    unsigned long long* fvbuf, float* __restrict__ out) {
  const int b = blockIdx.x;
  const int tid = threadIdx.x;
  const int lane = tid & 63;
  const int w = tid >> 6;             // wave id = local row
  const int r = b * ROWS_PB + w;      // this wave's global row
  const int e0 = tid * 4;             // first of 4 gathered entries

  __shared__ __align__(16) float fvs[2][K_TAGS];
  __shared__ __align__(16) float wredM[2][4];  // slot-buffered lagged blockmax
  __shared__ float wredS[4];

  // register-resident, log2-scaled matrix slices (constant across steps)
  float ta2[16], df2[16];
  {
    const float2* taP = reinterpret_cast<const float2*>(ta + (size_t)r * K_TAGS) + lane;
    const float2* tiP = reinterpret_cast<const float2*>(ti + (size_t)r * K_TAGS) + lane;
#pragma unroll
    for (int c = 0; c < C8; ++c) {
      float2 a = taP[64 * c];
      float2 i_ = tiP[64 * c];
      ta2[2 * c] = a.x * LOG2E;
      df2[2 * c] = (i_.x - a.x) * LOG2E;
      ta2[2 * c + 1] = a.y * LOG2E;
      df2[2 * c + 1] = (i_.y - a.y) * LOG2E;
    }
  }
  const float bmax2 = __int_as_float(*bmax_p) * LOG2E;

  // init lagged-max buffers: max(fv_0) = 0 (START row), used at t=0
  if (tid < 8) wredM[tid >> 2][tid & 3] = 0.0f;

  // publish initial state s_0 (tag 1) into slot 0
  if (tid < ROWS_PB) {
    int rr = b * ROWS_PB + tid;
    float v = (rr == START_TAG) ? 0.0f : NEGV * LOG2E;
    st_agent_u64(&fvbuf[rr],
                 (1ull << 32) | (unsigned long long)__float_as_uint(v));
  }

  for (int t = 0; t < T_STEPS; ++t) {
    const int slot = t & 1;
    const unsigned want = (unsigned)(t + 1);
    const float g = gate[t];            // broadcast load, hidden under poll
    float featv = 0.f;
    if (lane == 0) featv = feats[(size_t)t * K_TAGS + r];

    // 1) pipelined poll: check older sample set while newer is in flight
    unsigned long long* ep = &fvbuf[slot * K_TAGS + e0];
    unsigned long long a0 = ld_agent_u64(ep + 0), a1 = ld_agent_u64(ep + 1),
                       a2 = ld_agent_u64(ep + 2), a3 = ld_agent_u64(ep + 3);
    unsigned long long b0 = ld_agent_u64(ep + 0), b1 = ld_agent_u64(ep + 1),
                       b2 = ld_agent_u64(ep + 2), b3 = ld_agent_u64(ep + 3);
    while (TAG(a0) < want || TAG(a1) < want || TAG(a2) < want || TAG(a3) < want) {
      a0 = b0; a1 = b1; a2 = b2; a3 = b3;
      b0 = ld_agent_u64(ep + 0); b1 = ld_agent_u64(ep + 1);
      b2 = ld_agent_u64(ep + 2); b3 = ld_agent_u64(ep + 3);
    }
    const float v0 = __uint_as_float((unsigned)a0);
    const float v1 = __uint_as_float((unsigned)a1);
    const float v2 = __uint_as_float((unsigned)a2);
    const float v3 = __uint_as_float((unsigned)a3);

    // 2) stash raw fv -> one barrier
    *reinterpret_cast<float4*>(&fvs[slot][e0]) = make_float4(v0, v1, v2, v3);
    __syncthreads();

    // 3) lagged shift: blockmax(fv_{t-1}) + bmax2 + margin (written at t-1)
    const float4 mp = *reinterpret_cast<const float4*>(&wredM[slot ^ 1][0]);
    const float shift =
        fmaxf(fmaxf(mp.x, mp.y), fmaxf(mp.z, mp.w)) + bmax2 + MARGIN2;

    // 4) 16 cells/lane: acc += 2^(ta2 + g*df2 + fv - shift); conflict-free b64
    float acc0 = 0.f, acc1 = 0.f;
    const float2* fp = reinterpret_cast<const float2*>(&fvs[slot][0]) + lane;
#pragma unroll
    for (int c = 0; c < C8; ++c) {
      float2 f = fp[64 * c];
      acc0 += exp2f(__builtin_fmaf(g, df2[2 * c], ta2[2 * c]) + (f.x - shift));
      acc1 += exp2f(__builtin_fmaf(g, df2[2 * c + 1], ta2[2 * c + 1]) + (f.y - shift));
    }
    float acc = acc0 + acc1;
#pragma unroll
    for (int off = 32; off; off >>= 1) acc += __shfl_xor(acc, off);

    // 5) lane0 finalizes + publishes (tag t+2) into the other slot
    if (lane == 0) {
      float fvnew = shift + __log2f(acc) + featv * LOG2E;  // -inf if acc==0: OK
      st_agent_u64(&fvbuf[(slot ^ 1) * K_TAGS + r],
                   ((unsigned long long)(unsigned)(t + 2) << 32) |
                       (unsigned long long)__float_as_uint(fvnew));
    }

    // 6) OFF critical path: wave max of fv_t -> wredM[slot] for step t+1.
    //    Race-free: this write precedes our arrival at t+1's barrier; readers
    //    of wredM[slot] at t+1 read after that barrier; the t+2 overwrite
    //    happens only after all blocks published t+1 (tag chain).
    float lm = fmaxf(fmaxf(v0, v1), fmaxf(v2, v3));
#pragma unroll
    for (int off = 32; off; off >>= 1) lm = fmaxf(lm, __shfl_xor(lm, off));
    if (lane == 0) wredM[slot][w] = lm;
  }

  // ---- terminal LSE by block 0 ----------------------------------------------
  if (b == 0) {
    const unsigned want = (unsigned)(T_STEPS + 1);
    unsigned long long* ep = &fvbuf[(T_STEPS & 1) * K_TAGS + e0];
    unsigned long long u0 = ld_agent_u64(ep + 0);
    unsigned long long u1 = ld_agent_u64(ep + 1);
    unsigned long long u2 = ld_agent_u64(ep + 2);
    unsigned long long u3 = ld_agent_u64(ep + 3);
    while (TAG(u0) < want || TAG(u1) < want || TAG(u2) < want || TAG(u3) < want) {
      u0 = ld_agent_u64(ep + 0);
      u1 = ld_agent_u64(ep + 1);
      u2 = ld_agent_u64(ep + 2);
      u3 = ld_agent_u64(ep + 3);
    }
    const float gt = *g_term_p;
    float term[4];
    const unsigned long long uu[4] = {u0, u1, u2, u3};
#pragma unroll
    for (int j = 0; j < 4; ++j) {
      const int k = e0 + j;
      float tis = ti[(size_t)STOP_TAG * K_TAGS + k];
      float tas = ta[(size_t)STOP_TAG * K_TAGS + k];
      term[j] = __uint_as_float((unsigned)uu[j]) +
                (tas + gt * (tis - tas)) * LOG2E;
    }
    float m = fmaxf(fmaxf(term[0], term[1]), fmaxf(term[2], term[3]));
#pragma unroll
    for (int off = 32; off; off >>= 1) m = fmaxf(m, __shfl_xor(m, off));
    if (lane == 0) wredM[0][w] = m;
    __syncthreads();
    const float M2 = fmaxf(fmaxf(wredM[0][0], wredM[0][1]),
                           fmaxf(wredM[0][2], wredM[0][3]));
    float e = exp2f(term[0] - M2) + exp2f(term[1] - M2) +
              exp2f(term[2] - M2) + exp2f(term[3] - M2);
#pragma unroll
    for (int off = 32; off; off >>= 1) e += __shfl_xor(e, off);
    if (lane == 0) wredS[w] = e;
    __syncthreads();
    if (tid == 0) {
      float s = wredS[0] + wredS[1] + wredS[2] + wredS[3];
      out[0] = (M2 + __log2f(s)) * LN2;
    }
  }
}

extern "C" void kernel_launch(void* const* d_in, const int* in_sizes, int n_in,
                              void* d_out, int out_size, void* d_ws, size_t ws_size,
                              hipStream_t stream) {
  (void)in_sizes; (void)n_in; (void)out_size; (void)ws_size;
  const float* feats = (const float*)d_in[0];
  const float* reps  = (const float*)d_in[1];
  const float* wc    = (const float*)d_in[2];
  const float* wu    = (const float*)d_in[3];
  const float* ti    = (const float*)d_in[4];
  const float* ta    = (const float*)d_in[5];
  const int*   spk   = (const int*)d_in[6];
  float* out = (float*)d_out;

  // ws layout: fvbuf[2][1024] u64 (16 KiB) | gate[8192] f32 | g_term f32 | bmax i32
  unsigned long long* fvbuf = (unsigned long long*)d_ws;
  float* gate  = (float*)((char*)d_ws + 2 * K_TAGS * sizeof(unsigned long long));
  float* gterm = gate + T_STEPS;
  int*   bmax  = (int*)(gterm + 1);

  init_ws_kernel<<<dim3(8), dim3(256), 0, stream>>>(fvbuf, bmax);
  // 8193 wave-sized jobs, 4 waves per block
  gate_kernel<<<dim3((T_STEPS + 1 + 3) / 4), dim3(256), 0, stream>>>(
      reps, wc, wu, spk, gate, gterm);
  bmax_kernel<<<dim3(512), dim3(256), 0, stream>>>(ti, ta, bmax);
  crf_kernel<<<dim3(NBLK), dim3(256), 0, stream>>>(feats, ti, ta, gate, gterm,
                                                   bmax, fvbuf, out);
}